// Round 20
// baseline (62.533 us; speedup 1.0000x reference)
//
#include <hip/hip_runtime.h>

typedef float f32x4 __attribute__((ext_vector_type(4)));
typedef int   i32x4 __attribute__((ext_vector_type(4)));
typedef unsigned u32x4 __attribute__((ext_vector_type(4)));
typedef short b16x8 __attribute__((ext_vector_type(8)));

__device__ __forceinline__ short f2b(float v) {   // f32 -> bf16 (RNE)
  union { float f; unsigned u; } x; x.f = v;
  unsigned r = x.u + 0x7FFFu + ((x.u >> 16) & 1u);
  return (short)(r >> 16);
}
__device__ __forceinline__ float b2f(short s) {   // bf16 -> f32
  union { unsigned u; float f; } x; x.u = ((unsigned)(unsigned short)s) << 16;
  return x.f;
}

#define WT_ELEMS   (9 * 128 * 128)     // fragment-linear: [k][og:8][kk:4][lane:64][8]
#define WOFF_ELEMS (9 * 32 * 128)      // fragment-linear: [k][fo:2][kk:4][lane:64][8]
#define XT_BYTES   (8u * 4096u * 128u * 2u)   // x_t[b][y*64+x][c] bf16 = 8 MB

// LDS arena (36352 B -> 4 blocks/CU)
#define WIN_OFF   0        // half-window: 5 x 36 pos x 128B = 23040 (sW aliases 0..26112)
#define COFS_OFF  23040    // cofsT: 288 * uint4 = 4608
#define WTA_OFF   27648    // wtA:   288 * f32x4 = 4608
#define OFFT_OFF  32256    // offT:  4096
#define ARENA_SZ  36352

// ---- prep: weights -> tap-major, FRAGMENT-LINEAR bf16 ----
__global__ __launch_bounds__(256) void prep_w(
    const float* __restrict__ w_off, const float* __restrict__ w_dcn,
    short* __restrict__ wT, short* __restrict__ wOffT)
{
  int t = blockIdx.x * 256 + threadIdx.x;
  int stride = gridDim.x * 256;
  for (int i = t; i < WT_ELEMS; i += stride) {
    int j    = i & 7;
    int lane = (i >> 3) & 63;
    int kk   = (i >> 9) & 3;
    int og   = (i >> 11) & 7;
    int k    = i >> 14;
    int o = og * 16 + (lane & 15);
    int c = kk * 32 + (lane >> 4) * 8 + j;
    wT[i] = f2b(w_dcn[o * 1152 + c * 9 + k]);
  }
  for (int i = t; i < WOFF_ELEMS; i += stride) {
    int j    = i & 7;
    int lane = (i >> 3) & 63;
    int kk   = (i >> 9) & 3;
    int fo   = (i >> 11) & 1;
    int k    = i >> 12;
    int o = fo * 16 + (lane & 15);
    int c = kk * 32 + (lane >> 4) * 8 + j;
    wOffT[i] = (o < 18) ? f2b(w_off[o * 1152 + c * 9 + k]) : (short)0;
  }
}

// ---- transpose x[b][c][y][w] f32 -> x_t[b][y][w][c] bf16 ----
__global__ __launch_bounds__(256) void transp(
    const float* __restrict__ xg, short* __restrict__ xt)
{
  __shared__ float tile[32][65];
  const int bid = blockIdx.x;
  const int b = bid >> 6, y = bid & 63;
  const int t = threadIdx.x;
  const float* src = xg + ((size_t)b << 19) + y * 64;
  short*       dst = xt + ((size_t)b << 19) + (size_t)y * 8192;

  for (int ct = 0; ct < 4; ++ct) {
    __syncthreads();
    int c_l = t >> 3, w0 = (t & 7) * 8;
    const float* p = src + (size_t)(ct * 32 + c_l) * 4096 + w0;
    f32x4 a0 = *(const f32x4*)p;
    f32x4 a1 = *(const f32x4*)(p + 4);
    #pragma unroll
    for (int i = 0; i < 4; ++i) { tile[c_l][w0 + i] = a0[i]; tile[c_l][w0 + 4 + i] = a1[i]; }
    __syncthreads();
    int w = t >> 2, j0 = (t & 3) * 8;
    b16x8 pk;
    #pragma unroll
    for (int j = 0; j < 8; ++j) pk[j] = f2b(tile[j0 + j][w]);
    *(b16x8*)(dst + w * 128 + ct * 32 + j0) = pk;
  }
}

// ---------- wave-private lerp: lane builds its own MFMA B-fragment ----------
// ccol = byte offset within 128B half-row: kkl*64 + (lane>>4)*16
__device__ __forceinline__ b16x8 lerp_frag(const char* win, const short* xb, int h,
                                           u32x4 co, f32x4 wv, int ccol) {
  b16x8 g[4];
  #pragma unroll
  for (int c = 0; c < 4; ++c) {
    unsigned ofs = co[c];
    if (ofs & 0x80000000u) {            // global fallback (rare)
      const short* gp = xb + (size_t)(ofs & 0x7fffffffu) * 128 + h * 64 + (ccol >> 1);
      g[c] = *(const b16x8*)gp;
    } else {                            // LDS half-window, XOR-swizzled
      unsigned key = ((ofs >> 7) & 7) << 4;
      g[c] = *(const b16x8*)(win + ofs + (ccol ^ key));
    }
  }
  b16x8 sfrag;
  #pragma unroll
  for (int j = 0; j < 8; ++j) {
    float v = wv[0] * b2f(g[0][j]) + wv[1] * b2f(g[1][j]) +
              wv[2] * b2f(g[2][j]) + wv[3] * b2f(g[3][j]);
    sfrag[j] = f2b(v);
  }
  return sfrag;
}

// ---- fused deformable conv: wave-private phase 2, zero tap barriers ----
// block = 32 px (b, ho, wo0..wo0+31), 256 threads = 4 waves.
// wave wv: px-group (wv&1)*16..+15, o-half (wv>>1)*64..+63.
__global__ __launch_bounds__(256, 4) void dcn_mfma(
    const short* __restrict__ xt, const float* __restrict__ b_off,
    const short* __restrict__ wT, const short* __restrict__ wOffT,
    float* __restrict__ out)
{
  __shared__ __align__(16) char arena[ARENA_SZ];

  char*     sW    = arena + WIN_OFF;            // phase-1 window 26112B (aliases win+cofsT head)
  char*     win   = arena + WIN_OFF;            // half-window 23040B
  unsigned* cofsT = (unsigned*)(arena + COFS_OFF);
  f32x4*    wtA   = (f32x4*)(arena + WTA_OFF);
  float*    offT  = (float*)(arena + OFFT_OFF);

  const int tid  = threadIdx.x;
  const int lane = tid & 63;
  const int wv_  = tid >> 6;
  const int bid  = blockIdx.x;
  const int swz  = (bid & 7) * 128 + (bid >> 3);   // batch -> one XCD (L2 locality)
  const int b    = swz >> 7;
  const int ho   = (swz >> 1) & 63;
  const int wo0  = (swz & 1) * 32;

  const int l15  = lane & 15;
  const int l4   = lane >> 4;

  const short* xb = xt + ((size_t)b << 19);

  // ---- stage phase-1 window: 3 rows x 34 cols x 128 ch (256B rows, rolled) ----
  #pragma unroll 1
  for (int i = 0; i < 7; ++i) {
    int s = tid + i * 256;
    if (s < 1632) {
      int p = s >> 4, cc = s & 15;
      int py = p / 34, pxw = p - py * 34;
      int y = ho - 1 + py, xw = wo0 + pxw - 1;
      bool v = ((unsigned)y < 64u) && ((unsigned)xw < 64u);
      b16x8 q = {0,0,0,0,0,0,0,0};
      if (v) q = *(const b16x8*)(xb + ((size_t)(y * 64 + xw) << 7) + cc * 8);
      *(b16x8*)(sW + p * 256 + ((cc * 16) ^ ((p & 7) << 4))) = q;
    }
  }
  __syncthreads();

  // ---- phase 1: offset conv (rolled; coalesced weight frags) ----
  f32x4 accP = {0.f, 0.f, 0.f, 0.f};
  const int fo = wv_ >> 1, fp = wv_ & 1;
  {
    const int bpx = fp * 16 + l15;
    #pragma unroll 1
    for (int k = 0; k < 9; ++k) {
      int ky = k / 3, kx = k - ky * 3;
      int p  = ky * 34 + bpx + kx;
      const short* wkf = wOffT + (((k * 2 + fo) * 4) << 9);
      #pragma unroll
      for (int kk = 0; kk < 4; ++kk) {
        int cf = kk * 32 + l4 * 8;
        b16x8 a  = *(const b16x8*)(wkf + (kk << 9) + lane * 8);
        b16x8 bb = *(const b16x8*)(sW + p * 256 + ((cf * 2) ^ ((p & 7) << 4)));
        accP = __builtin_amdgcn_mfma_f32_16x16x32_bf16(a, bb, accP, 0, 0, 0);
      }
    }
  }
  {
    int px = fp * 16 + l15;
    int ob = fo * 16 + l4 * 4;
    #pragma unroll
    for (int r = 0; r < 4; ++r)
      offT[(ob + r) * 32 + px] = accP[r];   // offT region is fresh (no alias)
  }
  __syncthreads();   // offT visible; phase-1 window reads done

  // ---- tables for ALL 9 taps: weights + encoded corner offsets ----
  #pragma unroll 1
  for (int i = 0; i < 2; ++i) {
    int item = tid + i * 256;
    if (item < 288) {
      int k = item >> 5, px = item & 31;
      int ky = k / 3, kx = k - ky * 3;
      float dy = offT[(2 * k) * 32 + px]     + b_off[2 * k];
      float dx = offT[(2 * k + 1) * 32 + px] + b_off[2 * k + 1];
      float yy = (float)(ho - 1 + ky) + dy;
      float xx = (float)(wo0 + px - 1 + kx) + dx;
      float y0f = floorf(yy), x0f = floorf(xx);
      float wy = yy - y0f, wx = xx - x0f;
      int y0 = (int)y0f, x0 = (int)x0f;
      int y1 = y0 + 1, x1 = x0 + 1;
      int cy0 = min(max(y0, 0), 63), cx0 = min(max(x0, 0), 63);
      int cy1 = min(max(y1, 0), 63), cx1 = min(max(x1, 0), 63);
      float vy0 = ((unsigned)y0 < 64u) ? 1.f : 0.f;
      float vy1 = ((unsigned)y1 < 64u) ? 1.f : 0.f;
      float vx0 = ((unsigned)x0 < 64u) ? 1.f : 0.f;
      float vx1 = ((unsigned)x1 < 64u) ? 1.f : 0.f;
      f32x4 wvv;
      wvv[0] = (1.f - wy) * (1.f - wx) * vy0 * vx0;
      wvv[1] = (1.f - wy) * wx         * vy0 * vx1;
      wvv[2] = wy         * (1.f - wx) * vy1 * vx0;
      wvv[3] = wy         * wx         * vy1 * vx1;
      int cys[4] = {cy0, cy0, cy1, cy1};
      int cxs[4] = {cx0, cx1, cx0, cx1};
      u32x4 enc;
      #pragma unroll
      for (int c = 0; c < 4; ++c) {
        int wr = cys[c] - (ho - 2);
        int wc = cxs[c] - (wo0 - 2);
        bool inw = ((unsigned)wr < 5u) && ((unsigned)wc < 36u);
        enc[c] = inw ? (unsigned)((wr * 36 + wc) * 128)      // 128B half-rows
                     : (0x80000000u | (unsigned)(cys[c] * 64 + cxs[c]));
      }
      *(u32x4*)&cofsT[item * 4] = enc;
      wtA[item] = wvv;
    }
  }
  __syncthreads();   // tables ready; sW dead (cofsT head overlap is post-barrier)

  // ---- phase 2: two channel halves; wave-private taps, no inner barriers ----
  const int pxg   = wv_ & 1;
  const int ohalf = wv_ >> 1;
  const int mypx  = pxg * 16 + l15;
  const int ccol0 = l4 * 16;            // lane's chunk byte offset within 64-ch kkl row

  f32x4 acc0 = {0,0,0,0}, acc1 = {0,0,0,0}, acc2 = {0,0,0,0}, acc3 = {0,0,0,0};

  #pragma unroll 1
  for (int h = 0; h < 2; ++h) {
    if (h) __syncthreads();  // all waves done reading h=0 window
    // stage half-window: rows ho-2..ho+2, cols wo0-2..wo0+33, channels h*64..+63
    #pragma unroll 1
    for (int i = 0; i < 6; ++i) {
      int s = tid + i * 256;
      if (s < 1440) {                     // 180 positions * 8 chunks
        int seg = s & 7, pos = s >> 3;
        int r = pos / 36, cc = pos - r * 36;
        int y = ho - 2 + r, x = wo0 - 2 + cc;
        bool v = ((unsigned)y < 64u) && ((unsigned)x < 64u);
        b16x8 q = {0,0,0,0,0,0,0,0};
        if (v) q = *(const b16x8*)(xb + ((size_t)(y * 64 + x) << 7) + h * 64 + seg * 8);
        *(b16x8*)(win + pos * 128 + ((seg * 16) ^ ((pos & 7) << 4))) = q;
      }
    }
    __syncthreads();   // window half ready

    #pragma unroll 1
    for (int k = 0; k < 9; ++k) {
      u32x4 co  = *(const u32x4*)&cofsT[(k * 32 + mypx) * 4];
      f32x4 wvv = wtA[k * 32 + mypx];
      #pragma unroll
      for (int kkl = 0; kkl < 2; ++kkl) {
        b16x8 sfrag = lerp_frag(win, xb, h, co, wvv, kkl * 64 + ccol0);
        const short* wk = wT + (((k * 8 + ohalf * 4) * 4 + 2 * h + kkl) << 9) + lane * 8;
        b16x8 w0 = *(const b16x8*)(wk);
        b16x8 w1 = *(const b16x8*)(wk + (4 << 9));     // og+1
        b16x8 w2 = *(const b16x8*)(wk + (8 << 9));     // og+2
        b16x8 w3 = *(const b16x8*)(wk + (12 << 9));    // og+3
        acc0 = __builtin_amdgcn_mfma_f32_16x16x32_bf16(w0, sfrag, acc0, 0, 0, 0);
        acc1 = __builtin_amdgcn_mfma_f32_16x16x32_bf16(w1, sfrag, acc1, 0, 0, 0);
        acc2 = __builtin_amdgcn_mfma_f32_16x16x32_bf16(w2, sfrag, acc2, 0, 0, 0);
        acc3 = __builtin_amdgcn_mfma_f32_16x16x32_bf16(w3, sfrag, acc3, 0, 0, 0);
      }
    }
  }

  // ---- epilogue: wave writes its o-half x 16 px ----
  {
    size_t base = ((size_t)b * 128) * 4096 + (size_t)ho * 64 + wo0 + pxg * 16;
    int o0 = ohalf * 64 + l4 * 4;
    #pragma unroll
    for (int r = 0; r < 4; ++r) {
      out[base + (size_t)(o0 + r) * 4096 + l15]      = acc0[r];
      out[base + (size_t)(o0 + 16 + r) * 4096 + l15] = acc1[r];
      out[base + (size_t)(o0 + 32 + r) * 4096 + l15] = acc2[r];
      out[base + (size_t)(o0 + 48 + r) * 4096 + l15] = acc3[r];
    }
  }
}

extern "C" void kernel_launch(void* const* d_in, const int* in_sizes, int n_in,
                              void* d_out, int out_size, void* d_ws, size_t ws_size,
                              hipStream_t stream) {
  const float* x     = (const float*)d_in[0];
  const float* w_off = (const float*)d_in[1];
  const float* b_off = (const float*)d_in[2];
  const float* w_dcn = (const float*)d_in[3];
  float* out = (float*)d_out;

  short* xt    = (short*)d_ws;                                    // 8,388,608 B
  short* wT    = (short*)((char*)d_ws + XT_BYTES);                // 294,912 B
  short* wOffT = (short*)((char*)d_ws + XT_BYTES + WT_ELEMS * 2); // 73,728 B

  hipLaunchKernelGGL(prep_w,   dim3(64),   dim3(256), 0, stream, w_off, w_dcn, wT, wOffT);
  hipLaunchKernelGGL(transp,   dim3(512),  dim3(256), 0, stream, x, xt);
  hipLaunchKernelGGL(dcn_mfma, dim3(1024), dim3(256), 0, stream, xt, b_off, wT, wOffT, out);
}

// Round 21
// 50.343 us; speedup vs baseline: 1.2421x; 1.2421x over previous
//
#include <hip/hip_runtime.h>

typedef float f32x2 __attribute__((ext_vector_type(2)));
typedef float f32x4 __attribute__((ext_vector_type(4)));
typedef int   i32x4 __attribute__((ext_vector_type(4)));
typedef unsigned u32x4 __attribute__((ext_vector_type(4)));
typedef short b16x8 __attribute__((ext_vector_type(8)));

__device__ __forceinline__ short f2b(float v) {   // f32 -> bf16 (RNE)
  union { float f; unsigned u; } x; x.f = v;
  unsigned r = x.u + 0x7FFFu + ((x.u >> 16) & 1u);
  return (short)(r >> 16);
}
__device__ __forceinline__ float b2f(short s) {   // bf16 -> f32
  union { unsigned u; float f; } x; x.u = ((unsigned)(unsigned short)s) << 16;
  return x.f;
}
__device__ __forceinline__ f32x2 up2(int d) {     // dword of 2 bf16 -> 2 f32
  union { unsigned u; float f; } a, b;
  a.u = (unsigned)d << 16;
  b.u = (unsigned)d & 0xffff0000u;
  f32x2 r; r[0] = a.f; r[1] = b.f; return r;
}

#define WT_ELEMS   (9 * 128 * 128)     // fragment-linear: [k][og:8][kk:4][lane:64][8]
#define WOFF_ELEMS (9 * 32 * 128)      // fragment-linear: [k][fo:2][kk:4][lane:64][8]
#define XT_BYTES   (8u * 4096u * 128u * 2u)   // x_t[b][y*64+x][c] bf16 = 8 MB

// LDS arena (40448 B total -> 4 blocks/CU)
#define WIN_OFF   0        // half-window: 5 x 36 pos x 128B = 23040 (sW aliases 0..26112)
#define SS0_OFF   23040    // sS0: 4096 (offT aliases here after phase 1)
#define SS1_OFF   27136    // sS1: 4096
#define COFS_OFF  31232    // cofsT: 288 * uint4 = 4608
#define WTA_OFF   35840    // wtA:   288 * f32x4 = 4608
#define ARENA_SZ  40448

// ---- prep: weights -> tap-major, FRAGMENT-LINEAR bf16 ----
__global__ __launch_bounds__(256) void prep_w(
    const float* __restrict__ w_off, const float* __restrict__ w_dcn,
    short* __restrict__ wT, short* __restrict__ wOffT)
{
  int t = blockIdx.x * 256 + threadIdx.x;
  int stride = gridDim.x * 256;
  for (int i = t; i < WT_ELEMS; i += stride) {
    int j    = i & 7;
    int lane = (i >> 3) & 63;
    int kk   = (i >> 9) & 3;
    int og   = (i >> 11) & 7;
    int k    = i >> 14;
    int o = og * 16 + (lane & 15);
    int c = kk * 32 + (lane >> 4) * 8 + j;
    wT[i] = f2b(w_dcn[o * 1152 + c * 9 + k]);
  }
  for (int i = t; i < WOFF_ELEMS; i += stride) {
    int j    = i & 7;
    int lane = (i >> 3) & 63;
    int kk   = (i >> 9) & 3;
    int fo   = (i >> 11) & 1;
    int k    = i >> 12;
    int o = fo * 16 + (lane & 15);
    int c = kk * 32 + (lane >> 4) * 8 + j;
    wOffT[i] = (o < 18) ? f2b(w_off[o * 1152 + c * 9 + k]) : (short)0;
  }
}

// ---- transpose x[b][c][y][w] f32 -> x_t[b][y][w][c] bf16 ----
__global__ __launch_bounds__(256) void transp(
    const float* __restrict__ xg, short* __restrict__ xt)
{
  __shared__ float tile[32][65];
  const int bid = blockIdx.x;
  const int b = bid >> 6, y = bid & 63;
  const int t = threadIdx.x;
  const float* src = xg + ((size_t)b << 19) + y * 64;
  short*       dst = xt + ((size_t)b << 19) + (size_t)y * 8192;

  for (int ct = 0; ct < 4; ++ct) {
    __syncthreads();
    int c_l = t >> 3, w0 = (t & 7) * 8;
    const float* p = src + (size_t)(ct * 32 + c_l) * 4096 + w0;
    f32x4 a0 = *(const f32x4*)p;
    f32x4 a1 = *(const f32x4*)(p + 4);
    #pragma unroll
    for (int i = 0; i < 4; ++i) { tile[c_l][w0 + i] = a0[i]; tile[c_l][w0 + 4 + i] = a1[i]; }
    __syncthreads();
    int w = t >> 2, j0 = (t & 3) * 8;
    b16x8 pk;
    #pragma unroll
    for (int j = 0; j < 8; ++j) pk[j] = f2b(tile[j0 + j][w]);
    *(b16x8*)(dst + w * 128 + ct * 32 + j0) = pk;
  }
}

// ---------- helpers ----------
// lerp one tap for one channel-half, PACKED pairs (v_pk_fma_f32 + cvt_pk):
// 4-weight dot form kept (per-lane op sequence mul,fma,fma,fma unchanged).
__device__ __forceinline__ void lerp_half(char* sbuf, const char* win, const short* xb,
                                          int h, const unsigned* cofsT, const f32x4* wtA,
                                          int k, int px_s, int cg) {
  u32x4 co = *(const u32x4*)&cofsT[(k * 32 + px_s) * 4];
  f32x4 wv = wtA[k * 32 + px_s];
  i32x4 g[4];
  #pragma unroll
  for (int c = 0; c < 4; ++c) {
    unsigned ofs = co[c];
    if (ofs & 0x80000000u) {            // global fallback (rare)
      const short* gp = xb + (size_t)(ofs & 0x7fffffffu) * 128 + h * 64 + cg * 8;
      g[c] = *(const i32x4*)gp;
    } else {                            // LDS half-window, XOR-swizzled
      unsigned key = ((ofs >> 7) & 7) << 4;
      g[c] = *(const i32x4*)(win + ofs + ((cg * 16) ^ key));
    }
  }
  f32x2 w0p; w0p[0] = wv[0]; w0p[1] = wv[0];
  f32x2 w1p; w1p[0] = wv[1]; w1p[1] = wv[1];
  f32x2 w2p; w2p[0] = wv[2]; w2p[1] = wv[2];
  f32x2 w3p; w3p[0] = wv[3]; w3p[1] = wv[3];
  i32x4 pk;
  #pragma unroll
  for (int d = 0; d < 4; ++d) {
    f32x2 acc = up2(g[0][d]) * w0p;     // v_pk_mul_f32
    acc += up2(g[1][d]) * w1p;          // v_pk_fma_f32
    acc += up2(g[2][d]) * w2p;
    acc += up2(g[3][d]) * w3p;
    int r;
    asm("v_cvt_pk_bf16_f32 %0, %1, %2" : "=v"(r) : "v"(acc[0]), "v"(acc[1]));
    pk[d] = r;
  }
  *(i32x4*)(sbuf + px_s * 128 + ((cg * 16) ^ ((px_s & 7) << 4))) = pk;
}

// load one (tap, half)'s weight fragments: 4 x contiguous base+lane*16B
__device__ __forceinline__ void load_wfrag_half(b16x8 (&w)[4], const short* wT,
                                                int k, int h, int wv_, int lane) {
  const int og0 = wv_ * 2;
  #pragma unroll
  for (int kkl = 0; kkl < 2; ++kkl) {
    w[kkl]     = *(const b16x8*)(wT + ((((k * 8 + og0)     * 4) + 2 * h + kkl) << 9) + lane * 8);
    w[2 + kkl] = *(const b16x8*)(wT + ((((k * 8 + og0 + 1) * 4) + 2 * h + kkl) << 9) + lane * 8);
  }
}

// MFMA one (tap, half): K=64 (2 kk steps), reg-held weights + LDS sS half
__device__ __forceinline__ void mfma_half(const char* sbuf, const b16x8 (&w)[4],
                                          int l15, int l4,
                                          f32x4& a00, f32x4& a01, f32x4& a10, f32x4& a11) {
  #pragma unroll
  for (int kkl = 0; kkl < 2; ++kkl) {
    int cl2 = kkl * 64 + l4 * 16;       // byte offset of 8-ch chunk within 128B row
    b16x8 b0 = *(const b16x8*)(sbuf + l15 * 128        + (cl2 ^ ((l15 & 7) << 4)));
    b16x8 b1 = *(const b16x8*)(sbuf + (16 + l15) * 128 + (cl2 ^ ((l15 & 7) << 4)));
    a00 = __builtin_amdgcn_mfma_f32_16x16x32_bf16(w[kkl],     b0, a00, 0, 0, 0);
    a01 = __builtin_amdgcn_mfma_f32_16x16x32_bf16(w[kkl],     b1, a01, 0, 0, 0);
    a10 = __builtin_amdgcn_mfma_f32_16x16x32_bf16(w[2 + kkl], b0, a10, 0, 0, 0);
    a11 = __builtin_amdgcn_mfma_f32_16x16x32_bf16(w[2 + kkl], b1, a11, 0, 0, 0);
  }
}

// ---- fused deformable conv: channel-split LDS window, packed lerp ----
// block = 32 px (b, ho, wo0..wo0+31), 256 threads = 4 waves.
__global__ __launch_bounds__(256, 4) void dcn_mfma(
    const short* __restrict__ xt, const float* __restrict__ b_off,
    const short* __restrict__ wT, const short* __restrict__ wOffT,
    float* __restrict__ out)
{
  __shared__ __align__(16) char arena[ARENA_SZ];

  char*     sW    = arena + WIN_OFF;            // phase-1 window 26112B (aliases win+sS0)
  char*     win   = arena + WIN_OFF;            // half-window 23040B
  char*     sS0   = arena + SS0_OFF;
  char*     sS1   = arena + SS1_OFF;
  float*    offT  = (float*)(arena + SS0_OFF);  // 4096B (dead before taps)
  unsigned* cofsT = (unsigned*)(arena + COFS_OFF);
  f32x4*    wtA   = (f32x4*)(arena + WTA_OFF);

  const int tid  = threadIdx.x;
  const int lane = tid & 63;
  const int wv_  = tid >> 6;
  const int bid  = blockIdx.x;
  const int swz  = (bid & 7) * 128 + (bid >> 3);   // batch -> one XCD (L2 locality)
  const int b    = swz >> 7;
  const int ho   = (swz >> 1) & 63;
  const int wo0  = (swz & 1) * 32;

  const int px_s = tid >> 3;       // 0..31
  const int cg   = tid & 7;        // 0..7
  const int l15  = lane & 15;
  const int l4   = lane >> 4;

  const short* xb = xt + ((size_t)b << 19);

  // ---- stage phase-1 window: 3 rows x 34 cols x 128 ch (256B rows, rolled) ----
  #pragma unroll 1
  for (int i = 0; i < 7; ++i) {
    int s = tid + i * 256;
    if (s < 1632) {
      int p = s >> 4, cc = s & 15;
      int py = p / 34, pxw = p - py * 34;
      int y = ho - 1 + py, xw = wo0 + pxw - 1;
      bool v = ((unsigned)y < 64u) && ((unsigned)xw < 64u);
      b16x8 q = {0,0,0,0,0,0,0,0};
      if (v) q = *(const b16x8*)(xb + ((size_t)(y * 64 + xw) << 7) + cc * 8);
      *(b16x8*)(sW + p * 256 + ((cc * 16) ^ ((p & 7) << 4))) = q;
    }
  }
  __syncthreads();

  // ---- phase 1: offset conv (rolled; coalesced weight frags) ----
  f32x4 accP = {0.f, 0.f, 0.f, 0.f};
  const int fo = wv_ >> 1, fp = wv_ & 1;
  {
    const int bpx = fp * 16 + l15;
    #pragma unroll 1
    for (int k = 0; k < 9; ++k) {
      int ky = k / 3, kx = k - ky * 3;
      int p  = ky * 34 + bpx + kx;
      const short* wkf = wOffT + (((k * 2 + fo) * 4) << 9);
      #pragma unroll
      for (int kk = 0; kk < 4; ++kk) {
        int cf = kk * 32 + l4 * 8;
        b16x8 a  = *(const b16x8*)(wkf + (kk << 9) + lane * 8);
        b16x8 bb = *(const b16x8*)(sW + p * 256 + ((cf * 2) ^ ((p & 7) << 4)));
        accP = __builtin_amdgcn_mfma_f32_16x16x32_bf16(a, bb, accP, 0, 0, 0);
      }
    }
  }
  __syncthreads();   // phase-1 window reads done BEFORE offT (aliased) write
  {
    int px = fp * 16 + l15;
    int ob = fo * 16 + l4 * 4;
    #pragma unroll
    for (int r = 0; r < 4; ++r)
      offT[(ob + r) * 32 + px] = accP[r];
  }
  __syncthreads();   // offT visible

  // ---- tables for ALL 9 taps: weights + encoded corner offsets ----
  #pragma unroll 1
  for (int i = 0; i < 2; ++i) {
    int item = tid + i * 256;
    if (item < 288) {
      int k = item >> 5, px = item & 31;
      int ky = k / 3, kx = k - ky * 3;
      float dy = offT[(2 * k) * 32 + px]     + b_off[2 * k];
      float dx = offT[(2 * k + 1) * 32 + px] + b_off[2 * k + 1];
      float yy = (float)(ho - 1 + ky) + dy;
      float xx = (float)(wo0 + px - 1 + kx) + dx;
      float y0f = floorf(yy), x0f = floorf(xx);
      float wy = yy - y0f, wx = xx - x0f;
      int y0 = (int)y0f, x0 = (int)x0f;
      int y1 = y0 + 1, x1 = x0 + 1;
      int cy0 = min(max(y0, 0), 63), cx0 = min(max(x0, 0), 63);
      int cy1 = min(max(y1, 0), 63), cx1 = min(max(x1, 0), 63);
      float vy0 = ((unsigned)y0 < 64u) ? 1.f : 0.f;
      float vy1 = ((unsigned)y1 < 64u) ? 1.f : 0.f;
      float vx0 = ((unsigned)x0 < 64u) ? 1.f : 0.f;
      float vx1 = ((unsigned)x1 < 64u) ? 1.f : 0.f;
      f32x4 wvv;
      wvv[0] = (1.f - wy) * (1.f - wx) * vy0 * vx0;
      wvv[1] = (1.f - wy) * wx         * vy0 * vx1;
      wvv[2] = wy         * (1.f - wx) * vy1 * vx0;
      wvv[3] = wy         * wx         * vy1 * vx1;
      int cys[4] = {cy0, cy0, cy1, cy1};
      int cxs[4] = {cx0, cx1, cx0, cx1};
      u32x4 enc;
      #pragma unroll
      for (int c = 0; c < 4; ++c) {
        int wr = cys[c] - (ho - 2);
        int wc = cxs[c] - (wo0 - 2);
        bool inw = ((unsigned)wr < 5u) && ((unsigned)wc < 36u);
        enc[c] = inw ? (unsigned)((wr * 36 + wc) * 128)      // 128B half-rows
                     : (0x80000000u | (unsigned)(cys[c] * 64 + cxs[c]));
      }
      *(u32x4*)&cofsT[item * 4] = enc;
      wtA[item] = wvv;
    }
  }
  __syncthreads();   // tables ready; sW dead

  // ---- phase 2: two channel halves; per half {stage 23KB window, 9 taps} ----
  f32x4 acc00 = {0,0,0,0}, acc01 = {0,0,0,0}, acc10 = {0,0,0,0}, acc11 = {0,0,0,0};
  b16x8 wreg[4], wnext[4];
  load_wfrag_half(wreg, wT, 0, 0, wv_, lane);

  #pragma unroll 1
  for (int h = 0; h < 2; ++h) {
    // stage half-window: rows ho-2..ho+2, cols wo0-2..wo0+33, channels h*64..+63
    #pragma unroll 1
    for (int i = 0; i < 6; ++i) {
      int s = tid + i * 256;
      if (s < 1440) {                     // 180 positions * 8 chunks
        int seg = s & 7, pos = s >> 3;
        int r = pos / 36, cc = pos - r * 36;
        int y = ho - 2 + r, x = wo0 - 2 + cc;
        bool v = ((unsigned)y < 64u) && ((unsigned)x < 64u);
        b16x8 q = {0,0,0,0,0,0,0,0};
        if (v) q = *(const b16x8*)(xb + ((size_t)(y * 64 + x) << 7) + h * 64 + seg * 8);
        *(b16x8*)(win + pos * 128 + ((seg * 16) ^ ((pos & 7) << 4))) = q;
      }
    }
    __syncthreads();   // window half ready (prior taps' win reads done pre-barrier)

    #pragma unroll 1
    for (int k = 0; k < 9; ++k) {
      char* sb = ((h * 9 + k) & 1) ? sS1 : sS0;
      lerp_half(sb, win, xb, h, cofsT, wtA, k, px_s, cg);
      if (k < 8)            load_wfrag_half(wnext, wT, k + 1, h, wv_, lane);
      else if (h == 0)      load_wfrag_half(wnext, wT, 0, 1, wv_, lane);
      __syncthreads();                    // sS(k) visible
      mfma_half(sb, wreg, l15, l4, acc00, acc01, acc10, acc11);
      #pragma unroll
      for (int i = 0; i < 4; ++i) wreg[i] = wnext[i];
    }
  }

  // ---- epilogue ----
  {
    size_t base = ((size_t)b * 128) * 4096 + (size_t)ho * 64 + wo0;
    int o0 = wv_ * 32 + l4 * 4;
    #pragma unroll
    for (int r = 0; r < 4; ++r) {
      out[base + (size_t)(o0 + r) * 4096 + l15]           = acc00[r];
      out[base + (size_t)(o0 + r) * 4096 + 16 + l15]      = acc01[r];
      out[base + (size_t)(o0 + 16 + r) * 4096 + l15]      = acc10[r];
      out[base + (size_t)(o0 + 16 + r) * 4096 + 16 + l15] = acc11[r];
    }
  }
}

extern "C" void kernel_launch(void* const* d_in, const int* in_sizes, int n_in,
                              void* d_out, int out_size, void* d_ws, size_t ws_size,
                              hipStream_t stream) {
  const float* x     = (const float*)d_in[0];
  const float* w_off = (const float*)d_in[1];
  const float* b_off = (const float*)d_in[2];
  const float* w_dcn = (const float*)d_in[3];
  float* out = (float*)d_out;

  short* xt    = (short*)d_ws;                                    // 8,388,608 B
  short* wT    = (short*)((char*)d_ws + XT_BYTES);                // 294,912 B
  short* wOffT = (short*)((char*)d_ws + XT_BYTES + WT_ELEMS * 2); // 73,728 B

  hipLaunchKernelGGL(prep_w,   dim3(64),   dim3(256), 0, stream, w_off, w_dcn, wT, wOffT);
  hipLaunchKernelGGL(transp,   dim3(512),  dim3(256), 0, stream, x, xt);
  hipLaunchKernelGGL(dcn_mfma, dim3(1024), dim3(256), 0, stream, xt, b_off, wT, wOffT, out);
}

// Round 22
// 45.685 us; speedup vs baseline: 1.3688x; 1.1020x over previous
//
#include <hip/hip_runtime.h>

typedef float f32x2 __attribute__((ext_vector_type(2)));
typedef float f32x4 __attribute__((ext_vector_type(4)));
typedef int   i32x4 __attribute__((ext_vector_type(4)));
typedef unsigned u32x4 __attribute__((ext_vector_type(4)));
typedef short b16x8 __attribute__((ext_vector_type(8)));

__device__ __forceinline__ short f2b(float v) {   // f32 -> bf16 (RNE)
  union { float f; unsigned u; } x; x.f = v;
  unsigned r = x.u + 0x7FFFu + ((x.u >> 16) & 1u);
  return (short)(r >> 16);
}
__device__ __forceinline__ float b2f(short s) {   // bf16 -> f32
  union { unsigned u; float f; } x; x.u = ((unsigned)(unsigned short)s) << 16;
  return x.f;
}
__device__ __forceinline__ f32x2 up2(int d) {     // dword of 2 bf16 -> 2 f32
  union { unsigned u; float f; } a, b;
  a.u = (unsigned)d << 16;
  b.u = (unsigned)d & 0xffff0000u;
  f32x2 r; r[0] = a.f; r[1] = b.f; return r;
}

#define WT_ELEMS   (9 * 128 * 128)     // fragment-linear: [k][og:8][kk:4][lane:64][8]
#define WOFF_ELEMS (9 * 32 * 128)      // fragment-linear: [k][fo:2][kk:4][lane:64][8]
#define XT_BYTES   (8u * 4096u * 128u * 2u)   // x_t[b][y*64+x][c] bf16 = 8 MB

// LDS arena (40448 B total -> 4 blocks/CU)
#define WIN_OFF   0        // half-window: 5 x 36 pos x 128B = 23040 (sW aliases 0..26112)
#define SS0_OFF   23040    // sS0: 4096 (offT aliases here after phase 1)
#define SS1_OFF   27136    // sS1: 4096
#define COFS_OFF  31232    // cofsT: 288 * uint4 = 4608
#define WTA_OFF   35840    // wtA:   288 * f32x4 = 4608
#define ARENA_SZ  40448

// ---- fused aux: blocks 0..511 transpose x; blocks 512..575 reorder weights ----
__global__ __launch_bounds__(256) void prep_all(
    const float* __restrict__ xg, const float* __restrict__ w_off,
    const float* __restrict__ w_dcn,
    short* __restrict__ xt, short* __restrict__ wT, short* __restrict__ wOffT)
{
  __shared__ float tile[32][65];
  const int bid = blockIdx.x;
  const int t   = threadIdx.x;

  if (bid < 512) {
    // ---- transpose x[b][c][y][w] f32 -> x_t[b][y][w][c] bf16 ----
    const int b = bid >> 6, y = bid & 63;
    const float* src = xg + ((size_t)b << 19) + y * 64;
    short*       dst = xt + ((size_t)b << 19) + (size_t)y * 8192;

    for (int ct = 0; ct < 4; ++ct) {
      __syncthreads();
      int c_l = t >> 3, w0 = (t & 7) * 8;
      const float* p = src + (size_t)(ct * 32 + c_l) * 4096 + w0;
      f32x4 a0 = *(const f32x4*)p;
      f32x4 a1 = *(const f32x4*)(p + 4);
      #pragma unroll
      for (int i = 0; i < 4; ++i) { tile[c_l][w0 + i] = a0[i]; tile[c_l][w0 + 4 + i] = a1[i]; }
      __syncthreads();
      int w = t >> 2, j0 = (t & 3) * 8;
      b16x8 pk;
      #pragma unroll
      for (int j = 0; j < 8; ++j) pk[j] = f2b(tile[j0 + j][w]);
      *(b16x8*)(dst + w * 128 + ct * 32 + j0) = pk;
    }
  } else {
    // ---- weights -> tap-major, FRAGMENT-LINEAR bf16 ----
    int tt = (bid - 512) * 256 + t;
    int stride = 64 * 256;
    for (int i = tt; i < WT_ELEMS; i += stride) {
      int j    = i & 7;
      int lane = (i >> 3) & 63;
      int kk   = (i >> 9) & 3;
      int og   = (i >> 11) & 7;
      int k    = i >> 14;
      int o = og * 16 + (lane & 15);
      int c = kk * 32 + (lane >> 4) * 8 + j;
      wT[i] = f2b(w_dcn[o * 1152 + c * 9 + k]);
    }
    for (int i = tt; i < WOFF_ELEMS; i += stride) {
      int j    = i & 7;
      int lane = (i >> 3) & 63;
      int kk   = (i >> 9) & 3;
      int fo   = (i >> 11) & 1;
      int k    = i >> 12;
      int o = fo * 16 + (lane & 15);
      int c = kk * 32 + (lane >> 4) * 8 + j;
      wOffT[i] = (o < 18) ? f2b(w_off[o * 1152 + c * 9 + k]) : (short)0;
    }
  }
}

// ---------- helpers ----------
// lerp one tap for one channel-half, PACKED pairs (v_pk_fma_f32 + cvt_pk):
// 4-weight dot form kept (per-lane op sequence mul,fma,fma,fma unchanged).
__device__ __forceinline__ void lerp_half(char* sbuf, const char* win, const short* xb,
                                          int h, const unsigned* cofsT, const f32x4* wtA,
                                          int k, int px_s, int cg) {
  u32x4 co = *(const u32x4*)&cofsT[(k * 32 + px_s) * 4];
  f32x4 wv = wtA[k * 32 + px_s];
  i32x4 g[4];
  #pragma unroll
  for (int c = 0; c < 4; ++c) {
    unsigned ofs = co[c];
    if (ofs & 0x80000000u) {            // global fallback (rare)
      const short* gp = xb + (size_t)(ofs & 0x7fffffffu) * 128 + h * 64 + cg * 8;
      g[c] = *(const i32x4*)gp;
    } else {                            // LDS half-window, XOR-swizzled
      unsigned key = ((ofs >> 7) & 7) << 4;
      g[c] = *(const i32x4*)(win + ofs + ((cg * 16) ^ key));
    }
  }
  f32x2 w0p; w0p[0] = wv[0]; w0p[1] = wv[0];
  f32x2 w1p; w1p[0] = wv[1]; w1p[1] = wv[1];
  f32x2 w2p; w2p[0] = wv[2]; w2p[1] = wv[2];
  f32x2 w3p; w3p[0] = wv[3]; w3p[1] = wv[3];
  i32x4 pk;
  #pragma unroll
  for (int d = 0; d < 4; ++d) {
    f32x2 acc = up2(g[0][d]) * w0p;     // v_pk_mul_f32
    acc += up2(g[1][d]) * w1p;          // v_pk_fma_f32
    acc += up2(g[2][d]) * w2p;
    acc += up2(g[3][d]) * w3p;
    int r;
    asm("v_cvt_pk_bf16_f32 %0, %1, %2" : "=v"(r) : "v"(acc[0]), "v"(acc[1]));
    pk[d] = r;
  }
  *(i32x4*)(sbuf + px_s * 128 + ((cg * 16) ^ ((px_s & 7) << 4))) = pk;
}

// load one (tap, half)'s weight fragments: 4 x contiguous base+lane*16B
__device__ __forceinline__ void load_wfrag_half(b16x8 (&w)[4], const short* wT,
                                                int k, int h, int wv_, int lane) {
  const int og0 = wv_ * 2;
  #pragma unroll
  for (int kkl = 0; kkl < 2; ++kkl) {
    w[kkl]     = *(const b16x8*)(wT + ((((k * 8 + og0)     * 4) + 2 * h + kkl) << 9) + lane * 8);
    w[2 + kkl] = *(const b16x8*)(wT + ((((k * 8 + og0 + 1) * 4) + 2 * h + kkl) << 9) + lane * 8);
  }
}

// MFMA one (tap, half): K=64 (2 kk steps), reg-held weights + LDS sS half
__device__ __forceinline__ void mfma_half(const char* sbuf, const b16x8 (&w)[4],
                                          int l15, int l4,
                                          f32x4& a00, f32x4& a01, f32x4& a10, f32x4& a11) {
  #pragma unroll
  for (int kkl = 0; kkl < 2; ++kkl) {
    int cl2 = kkl * 64 + l4 * 16;       // byte offset of 8-ch chunk within 128B row
    b16x8 b0 = *(const b16x8*)(sbuf + l15 * 128        + (cl2 ^ ((l15 & 7) << 4)));
    b16x8 b1 = *(const b16x8*)(sbuf + (16 + l15) * 128 + (cl2 ^ ((l15 & 7) << 4)));
    a00 = __builtin_amdgcn_mfma_f32_16x16x32_bf16(w[kkl],     b0, a00, 0, 0, 0);
    a01 = __builtin_amdgcn_mfma_f32_16x16x32_bf16(w[kkl],     b1, a01, 0, 0, 0);
    a10 = __builtin_amdgcn_mfma_f32_16x16x32_bf16(w[2 + kkl], b0, a10, 0, 0, 0);
    a11 = __builtin_amdgcn_mfma_f32_16x16x32_bf16(w[2 + kkl], b1, a11, 0, 0, 0);
  }
}

// ---- fused deformable conv: channel-split LDS window, packed lerp ----
// block = 32 px (b, ho, wo0..wo0+31), 256 threads = 4 waves.
__global__ __launch_bounds__(256, 4) void dcn_mfma(
    const short* __restrict__ xt, const float* __restrict__ b_off,
    const short* __restrict__ wT, const short* __restrict__ wOffT,
    float* __restrict__ out)
{
  __shared__ __align__(16) char arena[ARENA_SZ];

  char*     sW    = arena + WIN_OFF;            // phase-1 window 26112B (aliases win+sS0)
  char*     win   = arena + WIN_OFF;            // half-window 23040B
  char*     sS0   = arena + SS0_OFF;
  char*     sS1   = arena + SS1_OFF;
  float*    offT  = (float*)(arena + SS0_OFF);  // 4096B (dead before taps)
  unsigned* cofsT = (unsigned*)(arena + COFS_OFF);
  f32x4*    wtA   = (f32x4*)(arena + WTA_OFF);

  const int tid  = threadIdx.x;
  const int lane = tid & 63;
  const int wv_  = tid >> 6;
  const int bid  = blockIdx.x;
  const int swz  = (bid & 7) * 128 + (bid >> 3);   // batch -> one XCD (L2 locality)
  const int b    = swz >> 7;
  const int ho   = (swz >> 1) & 63;
  const int wo0  = (swz & 1) * 32;

  const int px_s = tid >> 3;       // 0..31
  const int cg   = tid & 7;        // 0..7
  const int l15  = lane & 15;
  const int l4   = lane >> 4;

  const short* xb = xt + ((size_t)b << 19);

  // ---- stage phase-1 window: 3 rows x 34 cols x 128 ch (256B rows, rolled) ----
  #pragma unroll 1
  for (int i = 0; i < 7; ++i) {
    int s = tid + i * 256;
    if (s < 1632) {
      int p = s >> 4, cc = s & 15;
      int py = p / 34, pxw = p - py * 34;
      int y = ho - 1 + py, xw = wo0 + pxw - 1;
      bool v = ((unsigned)y < 64u) && ((unsigned)xw < 64u);
      b16x8 q = {0,0,0,0,0,0,0,0};
      if (v) q = *(const b16x8*)(xb + ((size_t)(y * 64 + xw) << 7) + cc * 8);
      *(b16x8*)(sW + p * 256 + ((cc * 16) ^ ((p & 7) << 4))) = q;
    }
  }
  __syncthreads();

  // ---- phase 1: offset conv (rolled; coalesced weight frags) ----
  f32x4 accP = {0.f, 0.f, 0.f, 0.f};
  const int fo = wv_ >> 1, fp = wv_ & 1;
  {
    const int bpx = fp * 16 + l15;
    #pragma unroll 1
    for (int k = 0; k < 9; ++k) {
      int ky = k / 3, kx = k - ky * 3;
      int p  = ky * 34 + bpx + kx;
      const short* wkf = wOffT + (((k * 2 + fo) * 4) << 9);
      #pragma unroll
      for (int kk = 0; kk < 4; ++kk) {
        int cf = kk * 32 + l4 * 8;
        b16x8 a  = *(const b16x8*)(wkf + (kk << 9) + lane * 8);
        b16x8 bb = *(const b16x8*)(sW + p * 256 + ((cf * 2) ^ ((p & 7) << 4)));
        accP = __builtin_amdgcn_mfma_f32_16x16x32_bf16(a, bb, accP, 0, 0, 0);
      }
    }
  }
  __syncthreads();   // phase-1 window reads done BEFORE offT (aliased) write
  {
    int px = fp * 16 + l15;
    int ob = fo * 16 + l4 * 4;
    #pragma unroll
    for (int r = 0; r < 4; ++r)
      offT[(ob + r) * 32 + px] = accP[r];
  }
  __syncthreads();   // offT visible

  // ---- tables for ALL 9 taps: weights + encoded corner offsets ----
  #pragma unroll 1
  for (int i = 0; i < 2; ++i) {
    int item = tid + i * 256;
    if (item < 288) {
      int k = item >> 5, px = item & 31;
      int ky = k / 3, kx = k - ky * 3;
      float dy = offT[(2 * k) * 32 + px]     + b_off[2 * k];
      float dx = offT[(2 * k + 1) * 32 + px] + b_off[2 * k + 1];
      float yy = (float)(ho - 1 + ky) + dy;
      float xx = (float)(wo0 + px - 1 + kx) + dx;
      float y0f = floorf(yy), x0f = floorf(xx);
      float wy = yy - y0f, wx = xx - x0f;
      int y0 = (int)y0f, x0 = (int)x0f;
      int y1 = y0 + 1, x1 = x0 + 1;
      int cy0 = min(max(y0, 0), 63), cx0 = min(max(x0, 0), 63);
      int cy1 = min(max(y1, 0), 63), cx1 = min(max(x1, 0), 63);
      float vy0 = ((unsigned)y0 < 64u) ? 1.f : 0.f;
      float vy1 = ((unsigned)y1 < 64u) ? 1.f : 0.f;
      float vx0 = ((unsigned)x0 < 64u) ? 1.f : 0.f;
      float vx1 = ((unsigned)x1 < 64u) ? 1.f : 0.f;
      f32x4 wvv;
      wvv[0] = (1.f - wy) * (1.f - wx) * vy0 * vx0;
      wvv[1] = (1.f - wy) * wx         * vy0 * vx1;
      wvv[2] = wy         * (1.f - wx) * vy1 * vx0;
      wvv[3] = wy         * wx         * vy1 * vx1;
      int cys[4] = {cy0, cy0, cy1, cy1};
      int cxs[4] = {cx0, cx1, cx0, cx1};
      u32x4 enc;
      #pragma unroll
      for (int c = 0; c < 4; ++c) {
        int wr = cys[c] - (ho - 2);
        int wc = cxs[c] - (wo0 - 2);
        bool inw = ((unsigned)wr < 5u) && ((unsigned)wc < 36u);
        enc[c] = inw ? (unsigned)((wr * 36 + wc) * 128)      // 128B half-rows
                     : (0x80000000u | (unsigned)(cys[c] * 64 + cxs[c]));
      }
      *(u32x4*)&cofsT[item * 4] = enc;
      wtA[item] = wvv;
    }
  }
  __syncthreads();   // tables ready; sW dead

  // ---- phase 2: two channel halves; per half {stage 23KB window, 9 taps} ----
  f32x4 acc00 = {0,0,0,0}, acc01 = {0,0,0,0}, acc10 = {0,0,0,0}, acc11 = {0,0,0,0};
  b16x8 wreg[4], wnext[4];
  load_wfrag_half(wreg, wT, 0, 0, wv_, lane);

  #pragma unroll 1
  for (int h = 0; h < 2; ++h) {
    // stage half-window: rows ho-2..ho+2, cols wo0-2..wo0+33, channels h*64..+63
    #pragma unroll 1
    for (int i = 0; i < 6; ++i) {
      int s = tid + i * 256;
      if (s < 1440) {                     // 180 positions * 8 chunks
        int seg = s & 7, pos = s >> 3;
        int r = pos / 36, cc = pos - r * 36;
        int y = ho - 2 + r, x = wo0 - 2 + cc;
        bool v = ((unsigned)y < 64u) && ((unsigned)x < 64u);
        b16x8 q = {0,0,0,0,0,0,0,0};
        if (v) q = *(const b16x8*)(xb + ((size_t)(y * 64 + x) << 7) + h * 64 + seg * 8);
        *(b16x8*)(win + pos * 128 + ((seg * 16) ^ ((pos & 7) << 4))) = q;
      }
    }
    __syncthreads();   // window half ready (prior taps' win reads done pre-barrier)

    #pragma unroll 1
    for (int k = 0; k < 9; ++k) {
      char* sb = ((h * 9 + k) & 1) ? sS1 : sS0;
      lerp_half(sb, win, xb, h, cofsT, wtA, k, px_s, cg);
      if (k < 8)            load_wfrag_half(wnext, wT, k + 1, h, wv_, lane);
      else if (h == 0)      load_wfrag_half(wnext, wT, 0, 1, wv_, lane);
      __syncthreads();                    // sS(k) visible
      mfma_half(sb, wreg, l15, l4, acc00, acc01, acc10, acc11);
      #pragma unroll
      for (int i = 0; i < 4; ++i) wreg[i] = wnext[i];
    }
  }

  // ---- epilogue ----
  {
    size_t base = ((size_t)b * 128) * 4096 + (size_t)ho * 64 + wo0;
    int o0 = wv_ * 32 + l4 * 4;
    #pragma unroll
    for (int r = 0; r < 4; ++r) {
      out[base + (size_t)(o0 + r) * 4096 + l15]           = acc00[r];
      out[base + (size_t)(o0 + r) * 4096 + 16 + l15]      = acc01[r];
      out[base + (size_t)(o0 + 16 + r) * 4096 + l15]      = acc10[r];
      out[base + (size_t)(o0 + 16 + r) * 4096 + 16 + l15] = acc11[r];
    }
  }
}

extern "C" void kernel_launch(void* const* d_in, const int* in_sizes, int n_in,
                              void* d_out, int out_size, void* d_ws, size_t ws_size,
                              hipStream_t stream) {
  const float* x     = (const float*)d_in[0];
  const float* w_off = (const float*)d_in[1];
  const float* b_off = (const float*)d_in[2];
  const float* w_dcn = (const float*)d_in[3];
  float* out = (float*)d_out;

  short* xt    = (short*)d_ws;                                    // 8,388,608 B
  short* wT    = (short*)((char*)d_ws + XT_BYTES);                // 294,912 B
  short* wOffT = (short*)((char*)d_ws + XT_BYTES + WT_ELEMS * 2); // 73,728 B

  hipLaunchKernelGGL(prep_all, dim3(576),  dim3(256), 0, stream,
                     x, w_off, w_dcn, xt, wT, wOffT);
  hipLaunchKernelGGL(dcn_mfma, dim3(1024), dim3(256), 0, stream, xt, b_off, wT, wOffT, out);
}

// Round 23
// 45.576 us; speedup vs baseline: 1.3720x; 1.0024x over previous
//
#include <hip/hip_runtime.h>

typedef float f32x2 __attribute__((ext_vector_type(2)));
typedef float f32x4 __attribute__((ext_vector_type(4)));
typedef int   i32x4 __attribute__((ext_vector_type(4)));
typedef unsigned u32x4 __attribute__((ext_vector_type(4)));
typedef short b16x8 __attribute__((ext_vector_type(8)));

#define BAR_LGKM() asm volatile("s_waitcnt lgkmcnt(0)\n\ts_barrier" ::: "memory")

__device__ __forceinline__ short f2b(float v) {   // f32 -> bf16 (RNE)
  union { float f; unsigned u; } x; x.f = v;
  unsigned r = x.u + 0x7FFFu + ((x.u >> 16) & 1u);
  return (short)(r >> 16);
}
__device__ __forceinline__ float b2f(short s) {   // bf16 -> f32
  union { unsigned u; float f; } x; x.u = ((unsigned)(unsigned short)s) << 16;
  return x.f;
}
__device__ __forceinline__ f32x2 up2(int d) {     // dword of 2 bf16 -> 2 f32
  union { unsigned u; float f; } a, b;
  a.u = (unsigned)d << 16;
  b.u = (unsigned)d & 0xffff0000u;
  f32x2 r; r[0] = a.f; r[1] = b.f; return r;
}

#define WT_ELEMS   (9 * 128 * 128)     // fragment-linear: [k][og:8][kk:4][lane:64][8]
#define WOFF_ELEMS (9 * 32 * 128)      // fragment-linear: [k][fo:2][kk:4][lane:64][8]
#define XT_BYTES   (8u * 4096u * 128u * 2u)   // x_t[b][y*64+x][c] bf16 = 8 MB

// LDS arena (40448 B total -> 4 blocks/CU)
#define WIN_OFF   0        // half-window: 5 x 36 pos x 128B = 23040 (sW aliases 0..26112)
#define SS0_OFF   23040    // sS0: 4096 (offT aliases here after phase 1)
#define SS1_OFF   27136    // sS1: 4096
#define COFS_OFF  31232    // cofsT: 288 * uint4 = 4608
#define WTA_OFF   35840    // wtA:   288 * f32x4 = 4608
#define ARENA_SZ  40448

// ---- fused aux: blocks 0..511 transpose x; blocks 512..575 reorder weights ----
__global__ __launch_bounds__(256) void prep_all(
    const float* __restrict__ xg, const float* __restrict__ w_off,
    const float* __restrict__ w_dcn,
    short* __restrict__ xt, short* __restrict__ wT, short* __restrict__ wOffT)
{
  __shared__ float tile[32][65];
  const int bid = blockIdx.x;
  const int t   = threadIdx.x;

  if (bid < 512) {
    // ---- transpose x[b][c][y][w] f32 -> x_t[b][y][w][c] bf16 ----
    const int b = bid >> 6, y = bid & 63;
    const float* src = xg + ((size_t)b << 19) + y * 64;
    short*       dst = xt + ((size_t)b << 19) + (size_t)y * 8192;

    for (int ct = 0; ct < 4; ++ct) {
      __syncthreads();
      int c_l = t >> 3, w0 = (t & 7) * 8;
      const float* p = src + (size_t)(ct * 32 + c_l) * 4096 + w0;
      f32x4 a0 = *(const f32x4*)p;
      f32x4 a1 = *(const f32x4*)(p + 4);
      #pragma unroll
      for (int i = 0; i < 4; ++i) { tile[c_l][w0 + i] = a0[i]; tile[c_l][w0 + 4 + i] = a1[i]; }
      __syncthreads();
      int w = t >> 2, j0 = (t & 3) * 8;
      b16x8 pk;
      #pragma unroll
      for (int j = 0; j < 8; ++j) pk[j] = f2b(tile[j0 + j][w]);
      *(b16x8*)(dst + w * 128 + ct * 32 + j0) = pk;
    }
  } else {
    // ---- weights -> tap-major, FRAGMENT-LINEAR bf16 ----
    int tt = (bid - 512) * 256 + t;
    int stride = 64 * 256;
    for (int i = tt; i < WT_ELEMS; i += stride) {
      int j    = i & 7;
      int lane = (i >> 3) & 63;
      int kk   = (i >> 9) & 3;
      int og   = (i >> 11) & 7;
      int k    = i >> 14;
      int o = og * 16 + (lane & 15);
      int c = kk * 32 + (lane >> 4) * 8 + j;
      wT[i] = f2b(w_dcn[o * 1152 + c * 9 + k]);
    }
    for (int i = tt; i < WOFF_ELEMS; i += stride) {
      int j    = i & 7;
      int lane = (i >> 3) & 63;
      int kk   = (i >> 9) & 3;
      int fo   = (i >> 11) & 1;
      int k    = i >> 12;
      int o = fo * 16 + (lane & 15);
      int c = kk * 32 + (lane >> 4) * 8 + j;
      wOffT[i] = (o < 18) ? f2b(w_off[o * 1152 + c * 9 + k]) : (short)0;
    }
  }
}

// ---------- helpers ----------
// lerp one tap for one channel-half, PACKED pairs (v_pk_fma_f32 + cvt_pk)
__device__ __forceinline__ void lerp_half(char* sbuf, const char* win, const short* xb,
                                          int h, const unsigned* cofsT, const f32x4* wtA,
                                          int k, int px_s, int cg) {
  u32x4 co = *(const u32x4*)&cofsT[(k * 32 + px_s) * 4];
  f32x4 wv = wtA[k * 32 + px_s];
  i32x4 g[4];
  #pragma unroll
  for (int c = 0; c < 4; ++c) {
    unsigned ofs = co[c];
    if (ofs & 0x80000000u) {            // global fallback (rare)
      const short* gp = xb + (size_t)(ofs & 0x7fffffffu) * 128 + h * 64 + cg * 8;
      g[c] = *(const i32x4*)gp;
    } else {                            // LDS half-window, XOR-swizzled
      unsigned key = ((ofs >> 7) & 7) << 4;
      g[c] = *(const i32x4*)(win + ofs + ((cg * 16) ^ key));
    }
  }
  f32x2 w0p; w0p[0] = wv[0]; w0p[1] = wv[0];
  f32x2 w1p; w1p[0] = wv[1]; w1p[1] = wv[1];
  f32x2 w2p; w2p[0] = wv[2]; w2p[1] = wv[2];
  f32x2 w3p; w3p[0] = wv[3]; w3p[1] = wv[3];
  i32x4 pk;
  #pragma unroll
  for (int d = 0; d < 4; ++d) {
    f32x2 acc = up2(g[0][d]) * w0p;     // v_pk_mul_f32
    acc += up2(g[1][d]) * w1p;          // v_pk_fma_f32
    acc += up2(g[2][d]) * w2p;
    acc += up2(g[3][d]) * w3p;
    int r;
    asm("v_cvt_pk_bf16_f32 %0, %1, %2" : "=v"(r) : "v"(acc[0]), "v"(acc[1]));
    pk[d] = r;
  }
  *(i32x4*)(sbuf + px_s * 128 + ((cg * 16) ^ ((px_s & 7) << 4))) = pk;
}

// load one (tap, half)'s weight fragments: 4 x contiguous base+lane*16B
__device__ __forceinline__ void load_wfrag_half(b16x8 (&w)[4], const short* wT,
                                                int k, int h, int wv_, int lane) {
  const int og0 = wv_ * 2;
  #pragma unroll
  for (int kkl = 0; kkl < 2; ++kkl) {
    w[kkl]     = *(const b16x8*)(wT + ((((k * 8 + og0)     * 4) + 2 * h + kkl) << 9) + lane * 8);
    w[2 + kkl] = *(const b16x8*)(wT + ((((k * 8 + og0 + 1) * 4) + 2 * h + kkl) << 9) + lane * 8);
  }
}

// MFMA one (tap, half): K=64 (2 kk steps), reg-held weights + LDS sS half
__device__ __forceinline__ void mfma_half(const char* sbuf, const b16x8 (&w)[4],
                                          int l15, int l4,
                                          f32x4& a00, f32x4& a01, f32x4& a10, f32x4& a11) {
  #pragma unroll
  for (int kkl = 0; kkl < 2; ++kkl) {
    int cl2 = kkl * 64 + l4 * 16;       // byte offset of 8-ch chunk within 128B row
    b16x8 b0 = *(const b16x8*)(sbuf + l15 * 128        + (cl2 ^ ((l15 & 7) << 4)));
    b16x8 b1 = *(const b16x8*)(sbuf + (16 + l15) * 128 + (cl2 ^ ((l15 & 7) << 4)));
    a00 = __builtin_amdgcn_mfma_f32_16x16x32_bf16(w[kkl],     b0, a00, 0, 0, 0);
    a01 = __builtin_amdgcn_mfma_f32_16x16x32_bf16(w[kkl],     b1, a01, 0, 0, 0);
    a10 = __builtin_amdgcn_mfma_f32_16x16x32_bf16(w[2 + kkl], b0, a10, 0, 0, 0);
    a11 = __builtin_amdgcn_mfma_f32_16x16x32_bf16(w[2 + kkl], b1, a11, 0, 0, 0);
  }
}

// ---- fused deformable conv: channel-split window, packed lerp, lgkm barriers ----
// block = 32 px (b, ho, wo0..wo0+31), 256 threads = 4 waves.
__global__ __launch_bounds__(256, 4) void dcn_mfma(
    const short* __restrict__ xt, const float* __restrict__ b_off,
    const short* __restrict__ wT, const short* __restrict__ wOffT,
    float* __restrict__ out)
{
  __shared__ __align__(16) char arena[ARENA_SZ];

  char*     sW    = arena + WIN_OFF;            // phase-1 window 26112B (aliases win+sS0)
  char*     win   = arena + WIN_OFF;            // half-window 23040B
  char*     sS0   = arena + SS0_OFF;
  char*     sS1   = arena + SS1_OFF;
  float*    offT  = (float*)(arena + SS0_OFF);  // 4096B (dead before taps)
  unsigned* cofsT = (unsigned*)(arena + COFS_OFF);
  f32x4*    wtA   = (f32x4*)(arena + WTA_OFF);

  const int tid  = threadIdx.x;
  const int lane = tid & 63;
  const int wv_  = tid >> 6;
  const int bid  = blockIdx.x;
  const int swz  = (bid & 7) * 128 + (bid >> 3);   // batch -> one XCD (L2 locality)
  const int b    = swz >> 7;
  const int ho   = (swz >> 1) & 63;
  const int wo0  = (swz & 1) * 32;

  const int px_s = tid >> 3;       // 0..31
  const int cg   = tid & 7;        // 0..7
  const int l15  = lane & 15;
  const int l4   = lane >> 4;

  const short* xb = xt + ((size_t)b << 19);

  // ---- stage phase-1 window: 3 rows x 34 cols x 128 ch (256B rows, rolled) ----
  #pragma unroll 1
  for (int i = 0; i < 7; ++i) {
    int s = tid + i * 256;
    if (s < 1632) {
      int p = s >> 4, cc = s & 15;
      int py = p / 34, pxw = p - py * 34;
      int y = ho - 1 + py, xw = wo0 + pxw - 1;
      bool v = ((unsigned)y < 64u) && ((unsigned)xw < 64u);
      b16x8 q = {0,0,0,0,0,0,0,0};
      if (v) q = *(const b16x8*)(xb + ((size_t)(y * 64 + xw) << 7) + cc * 8);
      *(b16x8*)(sW + p * 256 + ((cc * 16) ^ ((p & 7) << 4))) = q;
    }
  }
  __syncthreads();

  // ---- phase 1: offset conv (rolled; coalesced weight frags) ----
  f32x4 accP = {0.f, 0.f, 0.f, 0.f};
  const int fo = wv_ >> 1, fp = wv_ & 1;
  {
    const int bpx = fp * 16 + l15;
    #pragma unroll 1
    for (int k = 0; k < 9; ++k) {
      int ky = k / 3, kx = k - ky * 3;
      int p  = ky * 34 + bpx + kx;
      const short* wkf = wOffT + (((k * 2 + fo) * 4) << 9);
      #pragma unroll
      for (int kk = 0; kk < 4; ++kk) {
        int cf = kk * 32 + l4 * 8;
        b16x8 a  = *(const b16x8*)(wkf + (kk << 9) + lane * 8);
        b16x8 bb = *(const b16x8*)(sW + p * 256 + ((cf * 2) ^ ((p & 7) << 4)));
        accP = __builtin_amdgcn_mfma_f32_16x16x32_bf16(a, bb, accP, 0, 0, 0);
      }
    }
  }
  __syncthreads();   // phase-1 window reads done BEFORE offT (aliased) write
  {
    int px = fp * 16 + l15;
    int ob = fo * 16 + l4 * 4;
    #pragma unroll
    for (int r = 0; r < 4; ++r)
      offT[(ob + r) * 32 + px] = accP[r];
  }
  __syncthreads();   // offT visible

  // ---- tables for ALL 9 taps: weights + encoded corner offsets ----
  #pragma unroll 1
  for (int i = 0; i < 2; ++i) {
    int item = tid + i * 256;
    if (item < 288) {
      int k = item >> 5, px = item & 31;
      int ky = k / 3, kx = k - ky * 3;
      float dy = offT[(2 * k) * 32 + px]     + b_off[2 * k];
      float dx = offT[(2 * k + 1) * 32 + px] + b_off[2 * k + 1];
      float yy = (float)(ho - 1 + ky) + dy;
      float xx = (float)(wo0 + px - 1 + kx) + dx;
      float y0f = floorf(yy), x0f = floorf(xx);
      float wy = yy - y0f, wx = xx - x0f;
      int y0 = (int)y0f, x0 = (int)x0f;
      int y1 = y0 + 1, x1 = x0 + 1;
      int cy0 = min(max(y0, 0), 63), cx0 = min(max(x0, 0), 63);
      int cy1 = min(max(y1, 0), 63), cx1 = min(max(x1, 0), 63);
      float vy0 = ((unsigned)y0 < 64u) ? 1.f : 0.f;
      float vy1 = ((unsigned)y1 < 64u) ? 1.f : 0.f;
      float vx0 = ((unsigned)x0 < 64u) ? 1.f : 0.f;
      float vx1 = ((unsigned)x1 < 64u) ? 1.f : 0.f;
      f32x4 wvv;
      wvv[0] = (1.f - wy) * (1.f - wx) * vy0 * vx0;
      wvv[1] = (1.f - wy) * wx         * vy0 * vx1;
      wvv[2] = wy         * (1.f - wx) * vy1 * vx0;
      wvv[3] = wy         * wx         * vy1 * vx1;
      int cys[4] = {cy0, cy0, cy1, cy1};
      int cxs[4] = {cx0, cx1, cx0, cx1};
      u32x4 enc;
      #pragma unroll
      for (int c = 0; c < 4; ++c) {
        int wr = cys[c] - (ho - 2);
        int wc = cxs[c] - (wo0 - 2);
        bool inw = ((unsigned)wr < 5u) && ((unsigned)wc < 36u);
        enc[c] = inw ? (unsigned)((wr * 36 + wc) * 128)      // 128B half-rows
                     : (0x80000000u | (unsigned)(cys[c] * 64 + cxs[c]));
      }
      *(u32x4*)&cofsT[item * 4] = enc;
      wtA[item] = wvv;
    }
  }
  __syncthreads();   // tables ready; sW dead

  // ---- phase 2: two channel halves; lgkm-only barriers (no vmcnt drain) ----
  // The wfrag global prefetch stays in flight across barriers; its wait moves
  // to the consuming mfma one tap later (r9-verified barrier construct).
  f32x4 acc00 = {0,0,0,0}, acc01 = {0,0,0,0}, acc10 = {0,0,0,0}, acc11 = {0,0,0,0};
  b16x8 wreg[4], wnext[4];
  load_wfrag_half(wreg, wT, 0, 0, wv_, lane);

  #pragma unroll 1
  for (int h = 0; h < 2; ++h) {
    // stage half-window: rows ho-2..ho+2, cols wo0-2..wo0+33, channels h*64..+63
    #pragma unroll 1
    for (int i = 0; i < 6; ++i) {
      int s = tid + i * 256;
      if (s < 1440) {                     // 180 positions * 8 chunks
        int seg = s & 7, pos = s >> 3;
        int r = pos / 36, cc = pos - r * 36;
        int y = ho - 2 + r, x = wo0 - 2 + cc;
        bool v = ((unsigned)y < 64u) && ((unsigned)x < 64u);
        b16x8 q = {0,0,0,0,0,0,0,0};
        if (v) q = *(const b16x8*)(xb + ((size_t)(y * 64 + x) << 7) + h * 64 + seg * 8);
        *(b16x8*)(win + pos * 128 + ((seg * 16) ^ ((pos & 7) << 4))) = q;
      }
    }
    BAR_LGKM();        // window half ready (ds_writes lgkm-drained)

    #pragma unroll 1
    for (int k = 0; k < 9; ++k) {
      char* sb = ((h * 9 + k) & 1) ? sS1 : sS0;
      lerp_half(sb, win, xb, h, cofsT, wtA, k, px_s, cg);
      if (k < 8)            load_wfrag_half(wnext, wT, k + 1, h, wv_, lane);
      else if (h == 0)      load_wfrag_half(wnext, wT, 0, 1, wv_, lane);
      BAR_LGKM();                         // sS(k) visible; prefetch stays in flight
      mfma_half(sb, wreg, l15, l4, acc00, acc01, acc10, acc11);
      #pragma unroll
      for (int i = 0; i < 4; ++i) wreg[i] = wnext[i];
    }
  }

  // ---- epilogue ----
  {
    size_t base = ((size_t)b * 128) * 4096 + (size_t)ho * 64 + wo0;
    int o0 = wv_ * 32 + l4 * 4;
    #pragma unroll
    for (int r = 0; r < 4; ++r) {
      out[base + (size_t)(o0 + r) * 4096 + l15]           = acc00[r];
      out[base + (size_t)(o0 + r) * 4096 + 16 + l15]      = acc01[r];
      out[base + (size_t)(o0 + 16 + r) * 4096 + l15]      = acc10[r];
      out[base + (size_t)(o0 + 16 + r) * 4096 + 16 + l15] = acc11[r];
    }
  }
}

extern "C" void kernel_launch(void* const* d_in, const int* in_sizes, int n_in,
                              void* d_out, int out_size, void* d_ws, size_t ws_size,
                              hipStream_t stream) {
  const float* x     = (const float*)d_in[0];
  const float* w_off = (const float*)d_in[1];
  const float* b_off = (const float*)d_in[2];
  const float* w_dcn = (const float*)d_in[3];
  float* out = (float*)d_out;

  short* xt    = (short*)d_ws;                                    // 8,388,608 B
  short* wT    = (short*)((char*)d_ws + XT_BYTES);                // 294,912 B
  short* wOffT = (short*)((char*)d_ws + XT_BYTES + WT_ELEMS * 2); // 73,728 B

  hipLaunchKernelGGL(prep_all, dim3(576),  dim3(256), 0, stream,
                     x, w_off, w_dcn, xt, wT, wOffT);
  hipLaunchKernelGGL(dcn_mfma, dim3(1024), dim3(256), 0, stream, xt, b_off, wT, wOffT, out);
}